// Round 2
// baseline (243.126 us; speedup 1.0000x reference)
//
#include <hip/hip_runtime.h>
#include <hip/hip_bf16.h>
#include <math.h>

// Problem dims (fixed): B=4, H=W=64, DIM=512, HEADS=64, QKV=8
// NPOS = B*H*W = 16384 positions, 4096 per batch.
// qs[b,h,w] = x[b,h,w,:] . wq_sum ; ks likewise.
// weights[...,p,q] = softmax_q(qs*ks[b,p,q]*SCALE)
// attn[b,h,w,p,d] = sum_q weights * v[b,h,w,q,d],  v = x @ w_v.

#define SCALE 0.35355339059327373f  // 8^-0.5

typedef __attribute__((ext_vector_type(8))) short s16x8;
typedef __attribute__((ext_vector_type(4))) float f32x4;

__device__ inline unsigned short f2bf(float f) {
    unsigned u = __float_as_uint(f);
    u += 0x7FFF + ((u >> 16) & 1);          // RNE
    return (unsigned short)(u >> 16);
}
__device__ inline float bf2f(unsigned short h) {
    return __uint_as_float(((unsigned)h) << 16);
}

// ---------------- tiny: column sums of w_q / w_k ----------------
__global__ __launch_bounds__(256) void k_wsum(const float* __restrict__ wq,
                                              const float* __restrict__ wk,
                                              float* __restrict__ wqs,
                                              float* __restrict__ wks) {
    int gw = blockIdx.x * 4 + (threadIdx.x >> 6);  // 0..1023
    int lane = threadIdx.x & 63;
    const float* src = (gw < 512) ? wq : wk;
    int c = gw & 511;
    const float4* row = (const float4*)(src + (size_t)c * 512);
    float4 a = row[lane * 2], b = row[lane * 2 + 1];
    float s = a.x + a.y + a.z + a.w + b.x + b.y + b.z + b.w;
#pragma unroll
    for (int off = 32; off; off >>= 1) s += __shfl_xor(s, off);
    if (lane == 0) {
        if (gw < 512) wqs[c] = s; else wks[c] = s;
    }
}

// ---------------- qs / ks: one wave per position ----------------
__global__ __launch_bounds__(256) void k_qsks(const float* __restrict__ x,
                                              const float* __restrict__ wqs,
                                              const float* __restrict__ wks,
                                              float* __restrict__ qs,
                                              float* __restrict__ ks) {
    int row = blockIdx.x * 4 + (threadIdx.x >> 6);  // 0..16383
    int lane = threadIdx.x & 63;
    const float4* xr = (const float4*)(x + (size_t)row * 512);
    const float4* q4 = (const float4*)wqs;
    const float4* k4 = (const float4*)wks;
    float sq = 0.f, sk = 0.f;
#pragma unroll
    for (int i = 0; i < 2; ++i) {
        float4 xv = xr[lane * 2 + i];
        float4 qv = q4[lane * 2 + i];
        float4 kv = k4[lane * 2 + i];
        sq += xv.x * qv.x + xv.y * qv.y + xv.z * qv.z + xv.w * qv.w;
        sk += xv.x * kv.x + xv.y * kv.y + xv.z * kv.z + xv.w * kv.w;
    }
#pragma unroll
    for (int off = 32; off; off >>= 1) {
        sq += __shfl_xor(sq, off);
        sk += __shfl_xor(sk, off);
    }
    if (lane == 0) { qs[row] = sq; ks[row] = sk; }
}

// ---------------- per-(b,p) row max/min of ks ----------------
__global__ __launch_bounds__(64) void k_minmax(const float* __restrict__ ks,
                                               float* __restrict__ kmax,
                                               float* __restrict__ kmin) {
    int bp = blockIdx.x;          // b*64 + p
    int lane = threadIdx.x;       // q
    float v = ks[bp * 64 + lane];
    float hi = v, lo = v;
#pragma unroll
    for (int off = 32; off; off >>= 1) {
        hi = fmaxf(hi, __shfl_xor(hi, off));
        lo = fminf(lo, __shfl_xor(lo, off));
    }
    if (lane == 0) { kmax[bp] = hi; kmin[bp] = lo; }
}

// ---------------- Wv -> transposed split-bf16 (hi/lo) ----------------
// wvT_h[n][k] = bf16(wv[k][n]); wvT_l[n][k] = bf16(wv[k][n] - hi)
__global__ __launch_bounds__(256) void k_prep(const float* __restrict__ wv,
                                              unsigned short* __restrict__ wh,
                                              unsigned short* __restrict__ wl) {
    __shared__ float tile[64][65];
    const int ti = blockIdx.x >> 3;       // k-tile
    const int tj = blockIdx.x & 7;        // n-tile
    const int r = threadIdx.x >> 4;       // 0..15
    const int c4 = (threadIdx.x & 15) * 4;
#pragma unroll
    for (int i = 0; i < 4; ++i) {
        int kl = r + i * 16;
        float4 v = *(const float4*)(wv + (size_t)(ti * 64 + kl) * 512 + tj * 64 + c4);
        tile[kl][c4 + 0] = v.x; tile[kl][c4 + 1] = v.y;
        tile[kl][c4 + 2] = v.z; tile[kl][c4 + 3] = v.w;
    }
    __syncthreads();
#pragma unroll
    for (int i = 0; i < 4; ++i) {
        int nl = r + i * 16;              // local n
        int n = tj * 64 + nl;
        ushort4 h4, l4;
        float v0 = tile[c4 + 0][nl], v1 = tile[c4 + 1][nl];
        float v2 = tile[c4 + 2][nl], v3 = tile[c4 + 3][nl];
        h4.x = f2bf(v0); l4.x = f2bf(v0 - bf2f(h4.x));
        h4.y = f2bf(v1); l4.y = f2bf(v1 - bf2f(h4.y));
        h4.z = f2bf(v2); l4.z = f2bf(v2 - bf2f(h4.z));
        h4.w = f2bf(v3); l4.w = f2bf(v3 - bf2f(h4.w));
        *(ushort4*)(wh + (size_t)n * 512 + ti * 64 + c4) = h4;
        *(ushort4*)(wl + (size_t)n * 512 + ti * 64 + c4) = l4;
    }
}

// ---------------- fused: V projection (MFMA split-bf16) + softmax-weighted sum ----
// One block = 16 consecutive positions. LDS 32KB: xh/xl bf16 tiles (phase 2),
// reused as vs[16][512] f32 (phase 3).
__global__ __launch_bounds__(256) void k_main(const float* __restrict__ x,
                                              const unsigned short* __restrict__ wh,
                                              const unsigned short* __restrict__ wl,
                                              const float* __restrict__ qs,
                                              const float* __restrict__ ks,
                                              const float* __restrict__ kmax,
                                              const float* __restrict__ kmin,
                                              float* __restrict__ out) {
    __shared__ char smem[32768];
    char* xhb = smem;                 // [16][512] bf16, XOR-swizzled 16B granules
    char* xlb = smem + 16384;
    float* vs = (float*)smem;         // [16][512] f32 (reuse after barrier)

    const int tid = threadIdx.x;
    const int r0 = blockIdx.x * 16;
    const int b = r0 >> 12;
    const int lane = tid & 63;
    const int wave = tid >> 6;

    // ---- phase 1: load 16 x-rows, split to bf16 hi/lo, store swizzled ----
    {
        const float4* xg = (const float4*)(x + (size_t)r0 * 512);
#pragma unroll
        for (int i = 0; i < 8; ++i) {
            int idx4 = i * 256 + tid;          // float4 index in [16][512]
            float4 v = xg[idx4];
            int row = idx4 >> 7;               // 128 float4 per row
            int col8 = idx4 & 127;             // 8-byte unit within bf16 row
            int g = col8 >> 1;                 // 16B granule index
            int off = (col8 & 1) * 8;
            int sbyte = row * 1024 + (((g ^ (row & 7)) << 4) + off);
            ushort4 h, l;
            h.x = f2bf(v.x); l.x = f2bf(v.x - bf2f(h.x));
            h.y = f2bf(v.y); l.y = f2bf(v.y - bf2f(h.y));
            h.z = f2bf(v.z); l.z = f2bf(v.z - bf2f(h.z));
            h.w = f2bf(v.w); l.w = f2bf(v.w - bf2f(h.w));
            *(ushort4*)(xhb + sbyte) = h;
            *(ushort4*)(xlb + sbyte) = l;
        }
    }
    __syncthreads();

    // ---- phase 2: V[16][512] = X @ Wv via mfma_f32_16x16x32_bf16, 3-product split
    f32x4 acc[8];
#pragma unroll
    for (int nt = 0; nt < 8; ++nt) acc[nt] = (f32x4){0.f, 0.f, 0.f, 0.f};
    const int arow = lane & 15;
    const int kgrp = lane >> 4;                 // 0..3
    const int swzbase = arow * 1024;
    const int amask = (arow & 7) << 4;
#pragma unroll 4
    for (int kstep = 0; kstep < 16; ++kstep) {
        int k0 = kstep * 32;
        int kb = (k0 + kgrp * 8) * 2;           // byte offset (16B-granule aligned)
        int sbyte = swzbase + ((kb ^ amask));   // XOR on granule bits 4..6
        s16x8 a_h = *(const s16x8*)(xhb + sbyte);
        s16x8 a_l = *(const s16x8*)(xlb + sbyte);
        const size_t koff = (size_t)(k0 + kgrp * 8);
#pragma unroll
        for (int nt = 0; nt < 8; ++nt) {
            int n = wave * 128 + nt * 16 + arow;
            s16x8 b_h = *(const s16x8*)(wh + (size_t)n * 512 + koff);
            s16x8 b_l = *(const s16x8*)(wl + (size_t)n * 512 + koff);
            acc[nt] = __builtin_amdgcn_mfma_f32_16x16x32_bf16(a_h, b_h, acc[nt], 0, 0, 0);
            acc[nt] = __builtin_amdgcn_mfma_f32_16x16x32_bf16(a_l, b_h, acc[nt], 0, 0, 0);
            acc[nt] = __builtin_amdgcn_mfma_f32_16x16x32_bf16(a_h, b_l, acc[nt], 0, 0, 0);
        }
    }
    __syncthreads();   // all xh/xl reads done before overwrite

    // D-frag: col = lane&15 (within 16-col tile), row = (lane>>4)*4 + reg
    {
        int rbase = (lane >> 4) * 4;
#pragma unroll
        for (int nt = 0; nt < 8; ++nt) {
            int col = wave * 128 + nt * 16 + arow;
#pragma unroll
            for (int r = 0; r < 4; ++r)
                vs[(rbase + r) * 512 + col] = acc[nt][r];
        }
    }
    __syncthreads();

    // ---- phase 3: softmax over q + weighted sum of V ----
    const int p = tid >> 2, sub = tid & 3;
    const float khi = kmax[b * 64 + p];
    const float klo = kmin[b * 64 + p];
    const float* krow = ks + b * 4096 + p * 64;
    float kv[16];
#pragma unroll
    for (int i = 0; i < 16; ++i) kv[i] = krow[sub + 4 * i];
    const size_t obase = (size_t)r0 * 512 + (size_t)p * 8;

    for (int m = 0; m < 16; ++m) {
        float s = qs[r0 + m] * SCALE;
        float rmax = (s >= 0.f) ? s * khi : s * klo;  // exact row max
        float den = 0.f;
        float a0 = 0, a1 = 0, a2 = 0, a3 = 0, a4 = 0, a5 = 0, a6 = 0, a7 = 0;
#pragma unroll
        for (int i = 0; i < 16; ++i) {
            float e = __expf(fmaf(s, kv[i], -rmax));
            den += e;
            const float4* vr = (const float4*)(&vs[m * 512 + (sub + 4 * i) * 8]);
            float4 v0 = vr[0], v1 = vr[1];
            a0 = fmaf(e, v0.x, a0); a1 = fmaf(e, v0.y, a1);
            a2 = fmaf(e, v0.z, a2); a3 = fmaf(e, v0.w, a3);
            a4 = fmaf(e, v1.x, a4); a5 = fmaf(e, v1.y, a5);
            a6 = fmaf(e, v1.z, a6); a7 = fmaf(e, v1.w, a7);
        }
#pragma unroll
        for (int off = 1; off <= 2; off <<= 1) {
            den += __shfl_xor(den, off);
            a0 += __shfl_xor(a0, off); a1 += __shfl_xor(a1, off);
            a2 += __shfl_xor(a2, off); a3 += __shfl_xor(a3, off);
            a4 += __shfl_xor(a4, off); a5 += __shfl_xor(a5, off);
            a6 += __shfl_xor(a6, off); a7 += __shfl_xor(a7, off);
        }
        if (sub == 0) {
            float inv = 1.0f / den;
            float4* o4 = (float4*)(out + obase + (size_t)m * 512);
            o4[0] = make_float4(a0 * inv, a1 * inv, a2 * inv, a3 * inv);
            o4[1] = make_float4(a4 * inv, a5 * inv, a6 * inv, a7 * inv);
        }
    }
}

extern "C" void kernel_launch(void* const* d_in, const int* in_sizes, int n_in,
                              void* d_out, int out_size, void* d_ws, size_t ws_size,
                              hipStream_t stream) {
    const float* x  = (const float*)d_in[0];
    const float* wq = (const float*)d_in[1];
    const float* wk = (const float*)d_in[2];
    const float* wv = (const float*)d_in[3];
    float* out = (float*)d_out;

    float* ws   = (float*)d_ws;
    float* qs   = ws;            // 16384
    float* ks   = ws + 16384;    // 16384
    float* wqs  = ws + 32768;    // 512
    float* wks  = ws + 33280;    // 512
    float* kmax = ws + 33792;    // 256
    float* kmin = ws + 34048;    // 256
    unsigned short* wvT_h = (unsigned short*)(ws + 34304);  // 512*512 bf16
    unsigned short* wvT_l = wvT_h + 262144;                 // 512*512 bf16

    hipLaunchKernelGGL(k_wsum,   dim3(256),  dim3(256), 0, stream, wq, wk, wqs, wks);
    hipLaunchKernelGGL(k_prep,   dim3(64),   dim3(256), 0, stream, wv, wvT_h, wvT_l);
    hipLaunchKernelGGL(k_qsks,   dim3(4096), dim3(256), 0, stream, x, wqs, wks, qs, ks);
    hipLaunchKernelGGL(k_minmax, dim3(256),  dim3(64),  0, stream, ks, kmax, kmin);
    hipLaunchKernelGGL(k_main,   dim3(1024), dim3(256), 0, stream, x, wvT_h, wvT_l,
                       qs, ks, kmax, kmin, out);
}

// Round 4
// 167.492 us; speedup vs baseline: 1.4516x; 1.4516x over previous
//
#include <hip/hip_runtime.h>
#include <hip/hip_bf16.h>
#include <math.h>

// Problem dims (fixed): B=4, H=W=64, DIM=512, HEADS=64, QKV=8
// NPOS = 16384 positions (4096/batch).
// qs[r] = x[r,:].wq_sum ; ks[r] likewise.
// weights[r,p,q] = softmax_q(qs[r]*ks[b,p,q]*SCALE)
// out[r, p*8+d] = sum_q weights * V[r, q*8+d],  V = x @ w_v.
//
// Pipeline: k_wsum -> k_prep (WvT split bf16 h/l) -> k_qsks -> k_prep2
//           -> k_vgemm (V into d_out) -> k_attn (reads V rows, overwrites with attn)

#define SCALE 0.35355339059327373f  // 8^-0.5

typedef __attribute__((ext_vector_type(8))) short s16x8;
typedef __attribute__((ext_vector_type(4))) float f32x4;

__device__ inline unsigned short f2bf(float f) {
    unsigned u = __float_as_uint(f);
    u += 0x7FFF + ((u >> 16) & 1);          // RNE
    return (unsigned short)(u >> 16);
}
__device__ inline float bf2f(unsigned short h) {
    return __uint_as_float(((unsigned)h) << 16);
}

// ---------------- tiny: column sums of w_q / w_k ----------------
__global__ __launch_bounds__(256) void k_wsum(const float* __restrict__ wq,
                                              const float* __restrict__ wk,
                                              float* __restrict__ wqs,
                                              float* __restrict__ wks) {
    int gw = blockIdx.x * 4 + (threadIdx.x >> 6);  // 0..1023
    int lane = threadIdx.x & 63;
    const float* src = (gw < 512) ? wq : wk;
    int c = gw & 511;
    const float4* row = (const float4*)(src + (size_t)c * 512);
    float4 a = row[lane * 2], b = row[lane * 2 + 1];
    float s = a.x + a.y + a.z + a.w + b.x + b.y + b.z + b.w;
#pragma unroll
    for (int off = 32; off; off >>= 1) s += __shfl_xor(s, off);
    if (lane == 0) {
        if (gw < 512) wqs[c] = s; else wks[c] = s;
    }
}

// ---------------- qs / ks: one wave per position ----------------
__global__ __launch_bounds__(256) void k_qsks(const float* __restrict__ x,
                                              const float* __restrict__ wqs,
                                              const float* __restrict__ wks,
                                              float* __restrict__ qs,
                                              float* __restrict__ ks) {
    int row = blockIdx.x * 4 + (threadIdx.x >> 6);  // 0..16383
    int lane = threadIdx.x & 63;
    const float4* xr = (const float4*)(x + (size_t)row * 512);
    const float4* q4 = (const float4*)wqs;
    const float4* k4 = (const float4*)wks;
    float sq = 0.f, sk = 0.f;
#pragma unroll
    for (int i = 0; i < 2; ++i) {
        float4 xv = xr[lane * 2 + i];
        float4 qv = q4[lane * 2 + i];
        float4 kv = k4[lane * 2 + i];
        sq += xv.x * qv.x + xv.y * qv.y + xv.z * qv.z + xv.w * qv.w;
        sk += xv.x * kv.x + xv.y * kv.y + xv.z * kv.z + xv.w * kv.w;
    }
#pragma unroll
    for (int off = 32; off; off >>= 1) {
        sq += __shfl_xor(sq, off);
        sk += __shfl_xor(sk, off);
    }
    if (lane == 0) { qs[row] = sq; ks[row] = sk; }
}

// ---------------- per-(b,p) row max/min of ks + packed L layout ----------------
// L[((b*64+q)*16 + (p&15))*4 + (p>>4)] = ks[b,p,q]  -> k_attn reads float4 over j
__global__ __launch_bounds__(64) void k_prep2(const float* __restrict__ ks,
                                              float* __restrict__ kmax,
                                              float* __restrict__ kmin,
                                              float* __restrict__ L) {
    int bp = blockIdx.x;          // b*64 + p
    int b = bp >> 6, p = bp & 63;
    int q = threadIdx.x;
    float v = ks[bp * 64 + q];
    float hi = v, lo = v;
#pragma unroll
    for (int off = 32; off; off >>= 1) {
        hi = fmaxf(hi, __shfl_xor(hi, off));
        lo = fminf(lo, __shfl_xor(lo, off));
    }
    if (q == 0) { kmax[bp] = hi; kmin[bp] = lo; }
    L[((b * 64 + q) * 16 + (p & 15)) * 4 + (p >> 4)] = v;
}

// ---------------- Wv -> transposed split-bf16 (hi/lo) ----------------
// wh[n][k] = bf16(wv[k][n]); wl[n][k] = bf16(wv[k][n] - hi)
__global__ __launch_bounds__(256) void k_prep(const float* __restrict__ wv,
                                              unsigned short* __restrict__ wh,
                                              unsigned short* __restrict__ wl) {
    __shared__ float tile[64][65];
    const int ti = blockIdx.x >> 3;       // k-tile
    const int tj = blockIdx.x & 7;        // n-tile
    const int r = threadIdx.x >> 4;       // 0..15
    const int c4 = (threadIdx.x & 15) * 4;
#pragma unroll
    for (int i = 0; i < 4; ++i) {
        int kl = r + i * 16;
        float4 v = *(const float4*)(wv + (size_t)(ti * 64 + kl) * 512 + tj * 64 + c4);
        tile[kl][c4 + 0] = v.x; tile[kl][c4 + 1] = v.y;
        tile[kl][c4 + 2] = v.z; tile[kl][c4 + 3] = v.w;
    }
    __syncthreads();
#pragma unroll
    for (int i = 0; i < 4; ++i) {
        int nl = r + i * 16;              // local n
        int n = tj * 64 + nl;
        ushort4 h4, l4;
        float v0 = tile[c4 + 0][nl], v1 = tile[c4 + 1][nl];
        float v2 = tile[c4 + 2][nl], v3 = tile[c4 + 3][nl];
        h4.x = f2bf(v0); l4.x = f2bf(v0 - bf2f(h4.x));
        h4.y = f2bf(v1); l4.y = f2bf(v1 - bf2f(h4.y));
        h4.z = f2bf(v2); l4.z = f2bf(v2 - bf2f(h4.z));
        h4.w = f2bf(v3); l4.w = f2bf(v3 - bf2f(h4.w));
        *(ushort4*)(wh + (size_t)n * 512 + ti * 64 + c4) = h4;
        *(ushort4*)(wl + (size_t)n * 512 + ti * 64 + c4) = l4;
    }
}

// ---------------- V-GEMM: V[16384][512] = X @ Wv (split-bf16, MFMA) ----------------
// BM=128, BN=256, BK=32, 512 threads (8 waves, 2x4 wave grid, 64x64 per wave).
// V written to d_out (k_attn consumes and overwrites it in place).
__global__ __launch_bounds__(512) void k_vgemm(const float* __restrict__ x,
                                               const unsigned short* __restrict__ wh,
                                               const unsigned short* __restrict__ wl,
                                               float* __restrict__ V) {
    __shared__ unsigned short Ah[128 * 32];   // [m][k] 64B rows
    __shared__ unsigned short Al[128 * 32];
    __shared__ unsigned short Bh[256 * 32];   // [n][k] 64B rows
    __shared__ unsigned short Bl[256 * 32];

    const int tid = threadIdx.x;
    const int wave = tid >> 6, lane = tid & 63;
    const int mblk = (int)(blockIdx.x >> 1) * 128;
    const int nblk = (int)(blockIdx.x & 1) * 256;
    const int wm = wave >> 2, wn = wave & 3;     // wave grid 2x4
    const int arow = lane & 15, kgrp = lane >> 4;

    f32x4 acc[4][4];
#pragma unroll
    for (int mt = 0; mt < 4; ++mt)
#pragma unroll
        for (int nt = 0; nt < 4; ++nt) acc[mt][nt] = (f32x4){0.f, 0.f, 0.f, 0.f};

    for (int step = 0; step < 16; ++step) {
        const int k0 = step * 32;
        // ---- stage A: X f32 -> bf16 hi/lo ----
#pragma unroll
        for (int i = 0; i < 2; ++i) {
            int f4 = tid + i * 512;           // 0..1023
            int row = f4 >> 3, c4 = f4 & 7;
            float4 v = *(const float4*)(x + (size_t)(mblk + row) * 512 + k0 + c4 * 4);
            ushort4 h, l;
            h.x = f2bf(v.x); l.x = f2bf(v.x - bf2f(h.x));
            h.y = f2bf(v.y); l.y = f2bf(v.y - bf2f(h.y));
            h.z = f2bf(v.z); l.z = f2bf(v.z - bf2f(h.z));
            h.w = f2bf(v.w); l.w = f2bf(v.w - bf2f(h.w));
            *(ushort4*)(Ah + row * 32 + c4 * 4) = h;
            *(ushort4*)(Al + row * 32 + c4 * 4) = l;
        }
        // ---- stage B: copy wh/wl 32-k slices ----
#pragma unroll
        for (int i = 0; i < 2; ++i) {
            int c = tid + i * 512;            // 16B chunk id, 0..1023
            int row = c >> 2, qt = c & 3;
            const size_t g = (size_t)(nblk + row) * 512 + k0 + qt * 8;
            *(s16x8*)(Bh + row * 32 + qt * 8) = *(const s16x8*)(wh + g);
            *(s16x8*)(Bl + row * 32 + qt * 8) = *(const s16x8*)(wl + g);
        }
        __syncthreads();

        // ---- compute: preload frags, 48 MFMA ----
        s16x8 ah[4], al[4], bh[4], bl[4];
#pragma unroll
        for (int mt = 0; mt < 4; ++mt) {
            int off = (wm * 64 + mt * 16 + arow) * 32 + kgrp * 8;
            ah[mt] = *(const s16x8*)(Ah + off);
            al[mt] = *(const s16x8*)(Al + off);
        }
#pragma unroll
        for (int nt = 0; nt < 4; ++nt) {
            int off = (wn * 64 + nt * 16 + arow) * 32 + kgrp * 8;
            bh[nt] = *(const s16x8*)(Bh + off);
            bl[nt] = *(const s16x8*)(Bl + off);
        }
#pragma unroll
        for (int mt = 0; mt < 4; ++mt)
#pragma unroll
            for (int nt = 0; nt < 4; ++nt) {
                acc[mt][nt] = __builtin_amdgcn_mfma_f32_16x16x32_bf16(ah[mt], bh[nt], acc[mt][nt], 0, 0, 0);
                acc[mt][nt] = __builtin_amdgcn_mfma_f32_16x16x32_bf16(al[mt], bh[nt], acc[mt][nt], 0, 0, 0);
                acc[mt][nt] = __builtin_amdgcn_mfma_f32_16x16x32_bf16(ah[mt], bl[nt], acc[mt][nt], 0, 0, 0);
            }
        __syncthreads();
    }

    // ---- epilogue: D-frag col = lane&15 (n), row = (lane>>4)*4 + r (m) ----
    const int rbase = (lane >> 4) * 4;
#pragma unroll
    for (int mt = 0; mt < 4; ++mt)
#pragma unroll
        for (int nt = 0; nt < 4; ++nt) {
            int col = nblk + wn * 64 + nt * 16 + arow;
#pragma unroll
            for (int r = 0; r < 4; ++r) {
                int row = mblk + wm * 64 + mt * 16 + rbase + r;
                V[(size_t)row * 512 + col] = acc[mt][nt][r];
            }
        }
}

// ---------------- attention: softmax over q + weighted V sum ----------------
// Block = 16 positions. V rows staged from io (=d_out) into LDS, then the same
// rows are overwritten with the attention output (block-private: safe).
// Thread = (wave=mgrp | p0 | sub): 4 p's per thread amortize each V read.
__global__ __launch_bounds__(256) void k_attn(float* __restrict__ io,
                                              const float* __restrict__ qs,
                                              const float* __restrict__ L,
                                              const float* __restrict__ kmax,
                                              const float* __restrict__ kmin) {
    __shared__ float vsm[16 * 512];
    const int tid = threadIdx.x;
    const int r0 = blockIdx.x * 16;
    const int b = r0 >> 12;

    // stage V (coalesced)
    {
        const float4* vg = (const float4*)(io + (size_t)r0 * 512);
        float4* s4 = (float4*)vsm;
#pragma unroll
        for (int i = 0; i < 8; ++i) s4[tid + 256 * i] = vg[tid + 256 * i];
    }
    __syncthreads();

    const int sub = tid & 3;
    const int p0 = (tid >> 2) & 15;
    const int wave = tid >> 6;

    float km[4], kn[4];
#pragma unroll
    for (int j = 0; j < 4; ++j) {
        km[j] = kmax[b * 64 + p0 + 16 * j];
        kn[j] = kmin[b * 64 + p0 + 16 * j];
    }
    const float* Lb = L + (size_t)b * 4096;   // [q][p0][j]

    for (int jj = 0; jj < 4; ++jj) {
        const int m = wave + jj * 4;
        const float t = qs[r0 + m] * SCALE;
        float rm[4];
#pragma unroll
        for (int j = 0; j < 4; ++j) rm[j] = (t >= 0.f) ? t * km[j] : t * kn[j];
        float den[4] = {0.f, 0.f, 0.f, 0.f};
        float acc[4][8];
#pragma unroll
        for (int j = 0; j < 4; ++j)
#pragma unroll
            for (int d = 0; d < 8; ++d) acc[j][d] = 0.f;

#pragma unroll 4
        for (int i = 0; i < 16; ++i) {
            const int q = sub + 4 * i;
            float4 kv = *(const float4*)(Lb + (q * 16 + p0) * 4);
            const float4* vr = (const float4*)(&vsm[m * 512 + q * 8]);
            float4 v0 = vr[0], v1 = vr[1];
            float va[8] = {v0.x, v0.y, v0.z, v0.w, v1.x, v1.y, v1.z, v1.w};
            float kvj[4] = {kv.x, kv.y, kv.z, kv.w};
#pragma unroll
            for (int j = 0; j < 4; ++j) {
                float e = __expf(fmaf(t, kvj[j], -rm[j]));
                den[j] += e;
#pragma unroll
                for (int d = 0; d < 8; ++d) acc[j][d] = fmaf(e, va[d], acc[j][d]);
            }
        }
        // reduce across the 4 sub-lanes
#pragma unroll
        for (int off = 1; off <= 2; off <<= 1) {
#pragma unroll
            for (int j = 0; j < 4; ++j) {
                den[j] += __shfl_xor(den[j], off);
#pragma unroll
                for (int d = 0; d < 8; ++d) acc[j][d] += __shfl_xor(acc[j][d], off);
            }
        }
        if (sub == 0) {
#pragma unroll
            for (int j = 0; j < 4; ++j) {
                float inv = 1.0f / den[j];
                float4* o4 = (float4*)(io + (size_t)(r0 + m) * 512 + (p0 + 16 * j) * 8);
                o4[0] = make_float4(acc[j][0] * inv, acc[j][1] * inv, acc[j][2] * inv, acc[j][3] * inv);
                o4[1] = make_float4(acc[j][4] * inv, acc[j][5] * inv, acc[j][6] * inv, acc[j][7] * inv);
            }
        }
    }
}

extern "C" void kernel_launch(void* const* d_in, const int* in_sizes, int n_in,
                              void* d_out, int out_size, void* d_ws, size_t ws_size,
                              hipStream_t stream) {
    const float* x  = (const float*)d_in[0];
    const float* wq = (const float*)d_in[1];
    const float* wk = (const float*)d_in[2];
    const float* wv = (const float*)d_in[3];
    float* out = (float*)d_out;

    float* ws   = (float*)d_ws;
    float* qs   = ws;                 // 16384
    float* ks   = ws + 16384;         // 16384
    float* wqs  = ws + 32768;         // 512
    float* wks  = ws + 33280;         // 512
    float* kmax = ws + 33792;         // 256
    float* kmin = ws + 34048;         // 256
    float* L    = ws + 34304;         // 16384 (4 * 64q * 16p0 * 4j)
    unsigned short* wvT_h = (unsigned short*)(ws + 50688);  // 512*512 bf16
    unsigned short* wvT_l = wvT_h + 262144;                 // 512*512 bf16

    hipLaunchKernelGGL(k_wsum,  dim3(256),  dim3(256), 0, stream, wq, wk, wqs, wks);
    hipLaunchKernelGGL(k_prep,  dim3(64),   dim3(256), 0, stream, wv, wvT_h, wvT_l);
    hipLaunchKernelGGL(k_qsks,  dim3(4096), dim3(256), 0, stream, x, wqs, wks, qs, ks);
    hipLaunchKernelGGL(k_prep2, dim3(256),  dim3(64),  0, stream, ks, kmax, kmin, L);
    hipLaunchKernelGGL(k_vgemm, dim3(256),  dim3(512), 0, stream, x, wvT_h, wvT_l, out);
    hipLaunchKernelGGL(k_attn,  dim3(1024), dim3(256), 0, stream, out, qs, L, kmax, kmin);
}

// Round 5
// 152.894 us; speedup vs baseline: 1.5902x; 1.0955x over previous
//
#include <hip/hip_runtime.h>
#include <hip/hip_bf16.h>
#include <math.h>

// Problem dims (fixed): B=4, H=W=64, DIM=512, HEADS=64, QKV=8
// NPOS = 16384 positions (4096/batch).
// qs[r] = x[r,:].wq_sum ; ks[r] likewise.
// weights[r,p,q] = softmax_q(qs[r]*ks[b,p,q]*SCALE)
// out[r, p*8+d] = sum_q weights * V[r, q*8+d],  V = x @ w_v.
//
// Pipeline: k_prep (wsum + WvT split-bf16) -> k_qsks -> k_prep2
//           -> k_vgemm (V into d_out) -> k_attn (in-place V -> attn)

#define SCALE 0.35355339059327373f   // 8^-0.5
#define LOG2E 1.4426950408889634f

typedef __attribute__((ext_vector_type(8))) short s16x8;
typedef __attribute__((ext_vector_type(4))) float f32x4;
typedef __attribute__((ext_vector_type(4))) unsigned int u32x4;

union frag_cast { u32x4 u; s16x8 s; };

__device__ __forceinline__ unsigned short f2bf(float f) {
    unsigned u = __float_as_uint(f);
    u += 0x7FFF + ((u >> 16) & 1);          // RNE
    return (unsigned short)(u >> 16);
}
__device__ __forceinline__ float bf2f(unsigned short h) {
    return __uint_as_float(((unsigned)h) << 16);
}

// async global->LDS, 16B per lane (dest must be wave-linear)
__device__ __forceinline__ void gl16(const void* g, void* l) {
    __builtin_amdgcn_global_load_lds(
        (const __attribute__((address_space(1))) unsigned int*)g,
        (__attribute__((address_space(3))) unsigned int*)l, 16, 0, 0);
}

// split two f32 into packed bf16 hi (trunc) and lo (RNE of residual)
__device__ __forceinline__ void split2(float f0, float f1, unsigned& h, unsigned& l) {
    unsigned u0 = __float_as_uint(f0), u1 = __float_as_uint(f1);
    h = __builtin_amdgcn_perm(u1, u0, 0x07060302u);   // {u1.hi16, u0.hi16}
    float l0 = f0 - __uint_as_float(u0 & 0xffff0000u);
    float l1 = f1 - __uint_as_float(u1 & 0xffff0000u);
    unsigned lp;
    asm("v_cvt_pk_bf16_f32 %0, %1, %2" : "=v"(lp) : "v"(l0), "v"(l1));
    l = lp;
}

// ---------------- combined prep: blocks 0..63 Wv transform, 64..319 w-sums ----
__global__ __launch_bounds__(256) void k_prep(const float* __restrict__ wq,
                                              const float* __restrict__ wk,
                                              const float* __restrict__ wv,
                                              float* __restrict__ wqs,
                                              float* __restrict__ wks,
                                              unsigned short* __restrict__ wh,
                                              unsigned short* __restrict__ wl) {
    __shared__ float tile[64][65];
    if (blockIdx.x >= 64) {
        // ---- column sums of w_q / w_k ----
        int gw = ((int)blockIdx.x - 64) * 4 + (threadIdx.x >> 6);  // 0..1023
        int lane = threadIdx.x & 63;
        const float* src = (gw < 512) ? wq : wk;
        int c = gw & 511;
        const float4* row = (const float4*)(src + (size_t)c * 512);
        float4 a = row[lane * 2], b = row[lane * 2 + 1];
        float s = a.x + a.y + a.z + a.w + b.x + b.y + b.z + b.w;
#pragma unroll
        for (int off = 32; off; off >>= 1) s += __shfl_xor(s, off);
        if (lane == 0) {
            if (gw < 512) wqs[c] = s; else wks[c] = s;
        }
        return;
    }
    // ---- Wv -> transposed split-bf16: wh[n][k], wl[n][k] ----
    const int ti = (int)blockIdx.x >> 3;  // k-tile
    const int tj = (int)blockIdx.x & 7;   // n-tile
    const int r = threadIdx.x >> 4;
    const int c4 = (threadIdx.x & 15) * 4;
#pragma unroll
    for (int i = 0; i < 4; ++i) {
        int kl = r + i * 16;
        float4 v = *(const float4*)(wv + (size_t)(ti * 64 + kl) * 512 + tj * 64 + c4);
        tile[kl][c4 + 0] = v.x; tile[kl][c4 + 1] = v.y;
        tile[kl][c4 + 2] = v.z; tile[kl][c4 + 3] = v.w;
    }
    __syncthreads();
#pragma unroll
    for (int i = 0; i < 4; ++i) {
        int nl = r + i * 16;
        int n = tj * 64 + nl;
        ushort4 h4, l4;
        float v0 = tile[c4 + 0][nl], v1 = tile[c4 + 1][nl];
        float v2 = tile[c4 + 2][nl], v3 = tile[c4 + 3][nl];
        h4.x = f2bf(v0); l4.x = f2bf(v0 - bf2f(h4.x));
        h4.y = f2bf(v1); l4.y = f2bf(v1 - bf2f(h4.y));
        h4.z = f2bf(v2); l4.z = f2bf(v2 - bf2f(h4.z));
        h4.w = f2bf(v3); l4.w = f2bf(v3 - bf2f(h4.w));
        *(ushort4*)(wh + (size_t)n * 512 + ti * 64 + c4) = h4;
        *(ushort4*)(wl + (size_t)n * 512 + ti * 64 + c4) = l4;
    }
}

// ---------------- qs / ks: one wave per position ----------------
__global__ __launch_bounds__(256) void k_qsks(const float* __restrict__ x,
                                              const float* __restrict__ wqs,
                                              const float* __restrict__ wks,
                                              float* __restrict__ qs,
                                              float* __restrict__ ks) {
    int row = (int)blockIdx.x * 4 + (threadIdx.x >> 6);  // 0..16383
    int lane = threadIdx.x & 63;
    const float4* xr = (const float4*)(x + (size_t)row * 512);
    const float4* q4 = (const float4*)wqs;
    const float4* k4 = (const float4*)wks;
    float sq = 0.f, sk = 0.f;
#pragma unroll
    for (int i = 0; i < 2; ++i) {
        float4 xv = xr[lane * 2 + i];
        float4 qv = q4[lane * 2 + i];
        float4 kv = k4[lane * 2 + i];
        sq += xv.x * qv.x + xv.y * qv.y + xv.z * qv.z + xv.w * qv.w;
        sk += xv.x * kv.x + xv.y * kv.y + xv.z * kv.z + xv.w * kv.w;
    }
#pragma unroll
    for (int off = 32; off; off >>= 1) {
        sq += __shfl_xor(sq, off);
        sk += __shfl_xor(sk, off);
    }
    if (lane == 0) { qs[row] = sq; ks[row] = sk; }
}

// ---------------- per-(b,p) row max/min of ks + packed L layout ----------------
// L[((b*64+q)*16 + (p&15))*4 + (p>>4)] = ks[b,p,q]
__global__ __launch_bounds__(64) void k_prep2(const float* __restrict__ ks,
                                              float* __restrict__ kmax,
                                              float* __restrict__ kmin,
                                              float* __restrict__ L) {
    int bp = blockIdx.x;          // b*64 + p
    int b = bp >> 6, p = bp & 63;
    int q = threadIdx.x;
    float v = ks[bp * 64 + q];
    float hi = v, lo = v;
#pragma unroll
    for (int off = 32; off; off >>= 1) {
        hi = fmaxf(hi, __shfl_xor(hi, off));
        lo = fminf(lo, __shfl_xor(lo, off));
    }
    if (q == 0) { kmax[bp] = hi; kmin[bp] = lo; }
    L[((b * 64 + q) * 16 + (p & 15)) * 4 + (p >> 4)] = v;
}

// ---------------- V-GEMM: V = X @ Wv, split-bf16 MFMA, global_load_lds staging --
// BM=128, BN=128, BK=32. grid = 128 M x 4 N = 512 blocks (2/CU). 8 waves (2x4),
// wave tile 64x32. LDS granule-swizzled (source pre-swizzle + swizzled read).
__global__ __launch_bounds__(512, 4) void k_vgemm(const float* __restrict__ x,
                                                  const unsigned short* __restrict__ wh,
                                                  const unsigned short* __restrict__ wl,
                                                  float* __restrict__ V) {
    __shared__ float Af[128 * 32];            // [row][32 f32] = 8 granules/row
    __shared__ unsigned short Bhs[128 * 32];  // [row][32 bf16] = 4 granules/row
    __shared__ unsigned short Bls[128 * 32];

    const int tid = threadIdx.x;
    const int wave = tid >> 6, lane = tid & 63;
    const int mblk = (int)(blockIdx.x >> 2) * 128;
    const int nblk = (int)(blockIdx.x & 3) * 128;
    const int wm = wave >> 2, wn = wave & 3;
    const int arow = lane & 15, kgrp = lane >> 4;

    // staging sources (inverse-swizzled granules; LDS dest is linear)
    const int ar = tid >> 3, ap = tid & 7;
    const float* gA0 = x + (size_t)(mblk + ar) * 512 + (size_t)(((ap ^ (ar & 7)) * 4));
    const float* gA1 = gA0 + (size_t)64 * 512;
    const int br = tid >> 2, bp = tid & 3;
    const size_t boff = (size_t)(nblk + br) * 512 + (size_t)((bp ^ (br & 3)) * 8);
    const unsigned short* gBh = wh + boff;
    const unsigned short* gBl = wl + boff;
    float* lA0 = Af + tid * 4;
    float* lA1 = Af + (tid + 512) * 4;
    unsigned short* lBh = Bhs + tid * 8;
    unsigned short* lBl = Bls + tid * 8;

    f32x4 acc[4][2];
#pragma unroll
    for (int mt = 0; mt < 4; ++mt)
#pragma unroll
        for (int nt = 0; nt < 2; ++nt) acc[mt][nt] = (f32x4){0.f, 0.f, 0.f, 0.f};

    for (int step = 0; step < 16; ++step) {
        gl16(gA0, lA0); gl16(gA1, lA1);
        gl16(gBh, lBh); gl16(gBl, lBl);
        gA0 += 32; gA1 += 32; gBh += 32; gBl += 32;
        __syncthreads();   // vmcnt(0) drain + barrier

        s16x8 ah[4], al[4], bh[2], bl[2];
        const int s = arow & 7;
#pragma unroll
        for (int mt = 0; mt < 4; ++mt) {
            const int rowa = wm * 64 + mt * 16 + arow;
            const float* base = Af + rowa * 32;
            f32x4 lo = *(const f32x4*)(base + (((kgrp * 2) ^ s) * 4));
            f32x4 hi = *(const f32x4*)(base + (((kgrp * 2 + 1) ^ s) * 4));
            unsigned h0, h1, h2, h3, l0, l1, l2, l3;
            split2(lo[0], lo[1], h0, l0);
            split2(lo[2], lo[3], h1, l1);
            split2(hi[0], hi[1], h2, l2);
            split2(hi[2], hi[3], h3, l3);
            frag_cast H, L;
            H.u = (u32x4){h0, h1, h2, h3};
            L.u = (u32x4){l0, l1, l2, l3};
            ah[mt] = H.s; al[mt] = L.s;
        }
#pragma unroll
        for (int nt = 0; nt < 2; ++nt) {
            const int rowb = wn * 32 + nt * 16 + arow;
            const int pb = kgrp ^ (rowb & 3);
            bh[nt] = *(const s16x8*)(Bhs + rowb * 32 + pb * 8);
            bl[nt] = *(const s16x8*)(Bls + rowb * 32 + pb * 8);
        }
#pragma unroll
        for (int mt = 0; mt < 4; ++mt)
#pragma unroll
            for (int nt = 0; nt < 2; ++nt) {
                acc[mt][nt] = __builtin_amdgcn_mfma_f32_16x16x32_bf16(ah[mt], bh[nt], acc[mt][nt], 0, 0, 0);
                acc[mt][nt] = __builtin_amdgcn_mfma_f32_16x16x32_bf16(al[mt], bh[nt], acc[mt][nt], 0, 0, 0);
                acc[mt][nt] = __builtin_amdgcn_mfma_f32_16x16x32_bf16(ah[mt], bl[nt], acc[mt][nt], 0, 0, 0);
            }
        __syncthreads();
    }

    // epilogue: D col = lane&15 (n), row = (lane>>4)*4 + r (m)
    const int rbase = (lane >> 4) * 4;
#pragma unroll
    for (int mt = 0; mt < 4; ++mt)
#pragma unroll
        for (int nt = 0; nt < 2; ++nt) {
            const int col = nblk + wn * 32 + nt * 16 + arow;
#pragma unroll
            for (int r = 0; r < 4; ++r) {
                const int row = mblk + wm * 64 + mt * 16 + rbase + r;
                V[(size_t)row * 512 + col] = acc[mt][nt][r];
            }
        }
}

// ---------------- attention: shuffle-free softmax + weighted V sum ----------------
// Block = 16 positions, in-place on io (=d_out). Thread (m = tid>>4, p0 = tid&15)
// owns ALL 64 q for 4 p-values (p = p0 + 16j): no cross-lane reduction.
// V-row reads are 16-lane LDS broadcasts; L staged in LDS.
__global__ __launch_bounds__(256) void k_attn(float* __restrict__ io,
                                              const float* __restrict__ qs,
                                              const float* __restrict__ L,
                                              const float* __restrict__ kmax,
                                              const float* __restrict__ kmin) {
    __shared__ float vsm[16 * 520];   // +8 pad per row: m-rows hit distinct banks
    __shared__ float Lsm[4096];
    const int tid = threadIdx.x;
    const int r0 = (int)blockIdx.x * 16;
    const int b = r0 >> 12;

    {
        const float4* vg = (const float4*)(io + (size_t)r0 * 512);
#pragma unroll
        for (int i = 0; i < 8; ++i) {
            int idx4 = tid + 256 * i;
            *(float4*)(vsm + (idx4 >> 7) * 520 + (idx4 & 127) * 4) = vg[idx4];
        }
        const float4* Lg = (const float4*)(L + (size_t)b * 4096);
#pragma unroll
        for (int i = 0; i < 4; ++i)
            *(float4*)(Lsm + (tid + 256 * i) * 4) = Lg[tid + 256 * i];
    }
    __syncthreads();

    const int m = tid >> 4, p0 = tid & 15;
    const float t2 = qs[r0 + m] * (SCALE * LOG2E);
    float rm2[4], den[4], acc[4][8];
#pragma unroll
    for (int j = 0; j < 4; ++j) {
        float khi = kmax[b * 64 + p0 + 16 * j];
        float klo = kmin[b * 64 + p0 + 16 * j];
        rm2[j] = (t2 >= 0.f) ? t2 * khi : t2 * klo;   // exact row max (base-2)
        den[j] = 0.f;
#pragma unroll
        for (int d = 0; d < 8; ++d) acc[j][d] = 0.f;
    }
    const float* vrow = vsm + m * 520;
#pragma unroll 4
    for (int q = 0; q < 64; ++q) {
        const float4 kv = *(const float4*)(Lsm + (q * 16 + p0) * 4);
        const f32x4 v0 = *(const f32x4*)(vrow + q * 8);
        const f32x4 v1 = *(const f32x4*)(vrow + q * 8 + 4);
        const float kvj[4] = {kv.x, kv.y, kv.z, kv.w};
#pragma unroll
        for (int j = 0; j < 4; ++j) {
            const float e = exp2f(fmaf(t2, kvj[j], -rm2[j]));   // arg <= 0
            den[j] += e;
            acc[j][0] = fmaf(e, v0[0], acc[j][0]);
            acc[j][1] = fmaf(e, v0[1], acc[j][1]);
            acc[j][2] = fmaf(e, v0[2], acc[j][2]);
            acc[j][3] = fmaf(e, v0[3], acc[j][3]);
            acc[j][4] = fmaf(e, v1[0], acc[j][4]);
            acc[j][5] = fmaf(e, v1[1], acc[j][5]);
            acc[j][6] = fmaf(e, v1[2], acc[j][6]);
            acc[j][7] = fmaf(e, v1[3], acc[j][7]);
        }
    }
#pragma unroll
    for (int j = 0; j < 4; ++j) {
        const float inv = 1.0f / den[j];
        float4* o = (float4*)(io + (size_t)(r0 + m) * 512 + (p0 + 16 * j) * 8);
        o[0] = make_float4(acc[j][0] * inv, acc[j][1] * inv, acc[j][2] * inv, acc[j][3] * inv);
        o[1] = make_float4(acc[j][4] * inv, acc[j][5] * inv, acc[j][6] * inv, acc[j][7] * inv);
    }
}

extern "C" void kernel_launch(void* const* d_in, const int* in_sizes, int n_in,
                              void* d_out, int out_size, void* d_ws, size_t ws_size,
                              hipStream_t stream) {
    const float* x  = (const float*)d_in[0];
    const float* wq = (const float*)d_in[1];
    const float* wk = (const float*)d_in[2];
    const float* wv = (const float*)d_in[3];
    float* out = (float*)d_out;

    float* ws   = (float*)d_ws;
    float* qs   = ws;                 // 16384
    float* ks   = ws + 16384;         // 16384
    float* wqs  = ws + 32768;         // 512
    float* wks  = ws + 33280;         // 512
    float* kmax = ws + 33792;         // 256
    float* kmin = ws + 34048;         // 256
    float* L    = ws + 34304;         // 16384
    unsigned short* wvT_h = (unsigned short*)(ws + 50688);  // 512*512 bf16
    unsigned short* wvT_l = wvT_h + 262144;                 // 512*512 bf16

    hipLaunchKernelGGL(k_prep,  dim3(320),  dim3(256), 0, stream, wq, wk, wv, wqs, wks, wvT_h, wvT_l);
    hipLaunchKernelGGL(k_qsks,  dim3(4096), dim3(256), 0, stream, x, wqs, wks, qs, ks);
    hipLaunchKernelGGL(k_prep2, dim3(256),  dim3(64),  0, stream, ks, kmax, kmin, L);
    hipLaunchKernelGGL(k_vgemm, dim3(512),  dim3(512), 0, stream, x, wvT_h, wvT_l, out);
    hipLaunchKernelGGL(k_attn,  dim3(1024), dim3(256), 0, stream, out, qs, L, kmax, kmin);
}

// Round 8
// 140.028 us; speedup vs baseline: 1.7363x; 1.0919x over previous
//
#include <hip/hip_runtime.h>
#include <hip/hip_bf16.h>
#include <math.h>

// Problem dims (fixed): B=4, H=W=64, DIM=512, HEADS=64, QKV=8
// NPOS = 16384 positions (4096/batch).
// qs[r] = x[r,:].wq_sum ; ks[r] likewise.
// weights[r,p,q] = softmax_q(qs[r]*ks[b,p,q]*SCALE)
// out[r, p*8+d] = sum_q weights * V[r, q*8+d],  V = x @ w_v.
//
// Pipeline: k_prep (wsum + WvT f16) -> k_qsks (qs/ks + x->f16) -> k_prep2
//           -> k_vgemm (pure-f16 MFMA, V into d_out) -> k_attn (in-place)

#define SCALE 0.35355339059327373f   // 8^-0.5
#define LOG2E 1.4426950408889634f

typedef __attribute__((ext_vector_type(8))) _Float16 f16x8;
typedef __attribute__((ext_vector_type(4))) _Float16 f16x4;
typedef __attribute__((ext_vector_type(4))) float f32x4;

// async global->LDS, 16B per lane (dest must be wave-linear)
__device__ __forceinline__ void gl16(const void* g, void* l) {
    __builtin_amdgcn_global_load_lds(
        (const __attribute__((address_space(1))) unsigned int*)g,
        (__attribute__((address_space(3))) unsigned int*)l, 16, 0, 0);
}

// ---------------- combined prep: blocks 0..63 Wv transform, 64..319 w-sums ----
__global__ __launch_bounds__(256) void k_prep(const float* __restrict__ wq,
                                              const float* __restrict__ wk,
                                              const float* __restrict__ wv,
                                              float* __restrict__ wqs,
                                              float* __restrict__ wks,
                                              _Float16* __restrict__ whf) {
    __shared__ float tile[64][65];
    if (blockIdx.x >= 64) {
        // ---- column sums of w_q / w_k ----
        int gw = ((int)blockIdx.x - 64) * 4 + (threadIdx.x >> 6);  // 0..1023
        int lane = threadIdx.x & 63;
        const float* src = (gw < 512) ? wq : wk;
        int c = gw & 511;
        const float4* row = (const float4*)(src + (size_t)c * 512);
        float4 a = row[lane * 2], b = row[lane * 2 + 1];
        float s = a.x + a.y + a.z + a.w + b.x + b.y + b.z + b.w;
#pragma unroll
        for (int off = 32; off; off >>= 1) s += __shfl_xor(s, off);
        if (lane == 0) {
            if (gw < 512) wqs[c] = s; else wks[c] = s;
        }
        return;
    }
    // ---- Wv -> transposed f16: whf[n][k] = (f16)wv[k][n] ----
    const int ti = (int)blockIdx.x >> 3;  // k-tile
    const int tj = (int)blockIdx.x & 7;   // n-tile
    const int r = threadIdx.x >> 4;
    const int c4 = (threadIdx.x & 15) * 4;
#pragma unroll
    for (int i = 0; i < 4; ++i) {
        int kl = r + i * 16;
        float4 v = *(const float4*)(wv + (size_t)(ti * 64 + kl) * 512 + tj * 64 + c4);
        tile[kl][c4 + 0] = v.x; tile[kl][c4 + 1] = v.y;
        tile[kl][c4 + 2] = v.z; tile[kl][c4 + 3] = v.w;
    }
    __syncthreads();
#pragma unroll
    for (int i = 0; i < 4; ++i) {
        int nl = r + i * 16;
        int n = tj * 64 + nl;
        f16x4 h4;
        h4[0] = (_Float16)tile[c4 + 0][nl];
        h4[1] = (_Float16)tile[c4 + 1][nl];
        h4[2] = (_Float16)tile[c4 + 2][nl];
        h4[3] = (_Float16)tile[c4 + 3][nl];
        *(f16x4*)(whf + (size_t)n * 512 + ti * 64 + c4) = h4;
    }
}

// ---------------- qs / ks + x -> f16 copy: one wave per position ----------------
__global__ __launch_bounds__(256) void k_qsks(const float* __restrict__ x,
                                              const float* __restrict__ wqs,
                                              const float* __restrict__ wks,
                                              float* __restrict__ qs,
                                              float* __restrict__ ks,
                                              _Float16* __restrict__ xh) {
    int row = (int)blockIdx.x * 4 + (threadIdx.x >> 6);  // 0..16383
    int lane = threadIdx.x & 63;
    const float4* xr = (const float4*)(x + (size_t)row * 512);
    const float4* q4 = (const float4*)wqs;
    const float4* k4 = (const float4*)wks;
    float4 xv0 = xr[lane * 2], xv1 = xr[lane * 2 + 1];
    float4 qv0 = q4[lane * 2], qv1 = q4[lane * 2 + 1];
    float4 kv0 = k4[lane * 2], kv1 = k4[lane * 2 + 1];
    float sq = xv0.x * qv0.x + xv0.y * qv0.y + xv0.z * qv0.z + xv0.w * qv0.w
             + xv1.x * qv1.x + xv1.y * qv1.y + xv1.z * qv1.z + xv1.w * qv1.w;
    float sk = xv0.x * kv0.x + xv0.y * kv0.y + xv0.z * kv0.z + xv0.w * kv0.w
             + xv1.x * kv1.x + xv1.y * kv1.y + xv1.z * kv1.z + xv1.w * kv1.w;
    // f16 copy of x (vgemm A operand)
    f16x8 hv;
    hv[0] = (_Float16)xv0.x; hv[1] = (_Float16)xv0.y;
    hv[2] = (_Float16)xv0.z; hv[3] = (_Float16)xv0.w;
    hv[4] = (_Float16)xv1.x; hv[5] = (_Float16)xv1.y;
    hv[6] = (_Float16)xv1.z; hv[7] = (_Float16)xv1.w;
    *(f16x8*)(xh + (size_t)row * 512 + lane * 8) = hv;
#pragma unroll
    for (int off = 32; off; off >>= 1) {
        sq += __shfl_xor(sq, off);
        sk += __shfl_xor(sk, off);
    }
    if (lane == 0) { qs[row] = sq; ks[row] = sk; }
}

// ---------------- per-(b,p) row max/min of ks + packed L layout ----------------
// L[((b*64+q)*16 + (p&15))*4 + (p>>4)] = ks[b,p,q]
__global__ __launch_bounds__(64) void k_prep2(const float* __restrict__ ks,
                                              float* __restrict__ kmax,
                                              float* __restrict__ kmin,
                                              float* __restrict__ L) {
    int bp = blockIdx.x;          // b*64 + p
    int b = bp >> 6, p = bp & 63;
    int q = threadIdx.x;
    float v = ks[bp * 64 + q];
    float hi = v, lo = v;
#pragma unroll
    for (int off = 32; off; off >>= 1) {
        hi = fmaxf(hi, __shfl_xor(hi, off));
        lo = fminf(lo, __shfl_xor(lo, off));
    }
    if (q == 0) { kmax[bp] = hi; kmin[bp] = lo; }
    L[((b * 64 + q) * 16 + (p & 15)) * 4 + (p >> 4)] = v;
}

// ---------------- V-GEMM: V = X @ Wv, pure-f16 single-product MFMA ----------------
// BM=128, BN=128, BK=64. grid 128x4 = 512 blocks, 256 threads (4 waves, 2x2),
// wave tile 64x64 (ds:MFMA = 0.5). Staging via global_load_lds w=16 with
// granule-XOR swizzle (pre-swizzled source + swizzled read; rule #21).
__global__ __launch_bounds__(256, 3) void k_vgemm(const _Float16* __restrict__ xh,
                                                  const _Float16* __restrict__ whf,
                                                  float* __restrict__ V) {
    __shared__ _Float16 As[128 * 64];   // [row][64 f16] = 8 granules/row
    __shared__ _Float16 Bs[128 * 64];

    const int tid = threadIdx.x;
    const int wave = tid >> 6, lane = tid & 63;
    const int mblk = (int)(blockIdx.x >> 2) * 128;
    const int nblk = (int)(blockIdx.x & 3) * 128;
    const int wm = wave >> 1, wn = wave & 1;
    const int arow = lane & 15, kgrp = lane >> 4;
    const int s7 = arow & 7;

    // staging pointers (inverse-swizzled source granules; LDS dest linear)
    const _Float16* pa[4]; const _Float16* pb[4];
    _Float16* la[4]; _Float16* lb[4];
#pragma unroll
    for (int i = 0; i < 4; ++i) {
        const int g = i * 256 + tid;          // granule 0..1023
        const int row = g >> 3, gp = g & 7;
        const int gs = (gp ^ (row & 7)) * 8;  // source k-offset (halves)
        pa[i] = xh + (size_t)(mblk + row) * 512 + gs;
        pb[i] = whf + (size_t)(nblk + row) * 512 + gs;
        la[i] = As + g * 8;
        lb[i] = Bs + g * 8;
    }

    f32x4 acc[4][4];
#pragma unroll
    for (int mt = 0; mt < 4; ++mt)
#pragma unroll
        for (int nt = 0; nt < 4; ++nt) acc[mt][nt] = (f32x4){0.f, 0.f, 0.f, 0.f};

    for (int step = 0; step < 8; ++step) {
#pragma unroll
        for (int i = 0; i < 4; ++i) gl16(pa[i], la[i]);
#pragma unroll
        for (int i = 0; i < 4; ++i) gl16(pb[i], lb[i]);
#pragma unroll
        for (int i = 0; i < 4; ++i) { pa[i] += 64; pb[i] += 64; }
        __syncthreads();   // drains vmcnt(0)

#pragma unroll
        for (int sub = 0; sub < 2; ++sub) {
            f16x8 a[4], b[4];
            const int pg = ((sub * 4 + kgrp) ^ s7) * 8;
#pragma unroll
            for (int mt = 0; mt < 4; ++mt)
                a[mt] = *(const f16x8*)(As + (wm * 64 + mt * 16 + arow) * 64 + pg);
#pragma unroll
            for (int nt = 0; nt < 4; ++nt)
                b[nt] = *(const f16x8*)(Bs + (wn * 64 + nt * 16 + arow) * 64 + pg);
#pragma unroll
            for (int mt = 0; mt < 4; ++mt)
#pragma unroll
                for (int nt = 0; nt < 4; ++nt)
                    acc[mt][nt] = __builtin_amdgcn_mfma_f32_16x16x32_f16(a[mt], b[nt], acc[mt][nt], 0, 0, 0);
        }
        __syncthreads();
    }

    // epilogue: D col = lane&15 (n), row = (lane>>4)*4 + r (m)
    const int rbase = (lane >> 4) * 4;
#pragma unroll
    for (int mt = 0; mt < 4; ++mt)
#pragma unroll
        for (int nt = 0; nt < 4; ++nt) {
            const int col = nblk + wn * 64 + nt * 16 + arow;
#pragma unroll
            for (int r = 0; r < 4; ++r) {
                const int row = mblk + wm * 64 + mt * 16 + rbase + r;
                V[(size_t)row * 512 + col] = acc[mt][nt][r];
            }
        }
}

// ---------------- attention: shuffle-free softmax + weighted V sum ----------------
// Block = 16 positions, in-place on io (=d_out). Thread (m = tid>>4, p0 = tid&15)
// owns ALL 64 q for 4 p-values (p = p0 + 16j): no cross-lane reduction.
__global__ __launch_bounds__(256) void k_attn(float* __restrict__ io,
                                              const float* __restrict__ qs,
                                              const float* __restrict__ L,
                                              const float* __restrict__ kmax,
                                              const float* __restrict__ kmin) {
    __shared__ float vsm[16 * 520];   // +8 pad per row
    __shared__ float Lsm[4096];
    const int tid = threadIdx.x;
    const int r0 = (int)blockIdx.x * 16;
    const int b = r0 >> 12;

    {
        const float4* vg = (const float4*)(io + (size_t)r0 * 512);
#pragma unroll
        for (int i = 0; i < 8; ++i) {
            int idx4 = tid + 256 * i;
            *(float4*)(vsm + (idx4 >> 7) * 520 + (idx4 & 127) * 4) = vg[idx4];
        }
        const float4* Lg = (const float4*)(L + (size_t)b * 4096);
#pragma unroll
        for (int i = 0; i < 4; ++i)
            *(float4*)(Lsm + (tid + 256 * i) * 4) = Lg[tid + 256 * i];
    }
    __syncthreads();

    const int m = tid >> 4, p0 = tid & 15;
    const float t2 = qs[r0 + m] * (SCALE * LOG2E);
    float rm2[4], den[4], acc[4][8];
#pragma unroll
    for (int j = 0; j < 4; ++j) {
        float khi = kmax[b * 64 + p0 + 16 * j];
        float klo = kmin[b * 64 + p0 + 16 * j];
        rm2[j] = (t2 >= 0.f) ? t2 * khi : t2 * klo;   // exact row max (base-2)
        den[j] = 0.f;
#pragma unroll
        for (int d = 0; d < 8; ++d) acc[j][d] = 0.f;
    }
    const float* vrow = vsm + m * 520;
#pragma unroll 4
    for (int q = 0; q < 64; ++q) {
        const float4 kv = *(const float4*)(Lsm + (q * 16 + p0) * 4);
        const f32x4 v0 = *(const f32x4*)(vrow + q * 8);
        const f32x4 v1 = *(const f32x4*)(vrow + q * 8 + 4);
        const float kvj[4] = {kv.x, kv.y, kv.z, kv.w};
#pragma unroll
        for (int j = 0; j < 4; ++j) {
            const float e = exp2f(fmaf(t2, kvj[j], -rm2[j]));   // arg <= 0
            den[j] += e;
            acc[j][0] = fmaf(e, v0[0], acc[j][0]);
            acc[j][1] = fmaf(e, v0[1], acc[j][1]);
            acc[j][2] = fmaf(e, v0[2], acc[j][2]);
            acc[j][3] = fmaf(e, v0[3], acc[j][3]);
            acc[j][4] = fmaf(e, v1[0], acc[j][4]);
            acc[j][5] = fmaf(e, v1[1], acc[j][5]);
            acc[j][6] = fmaf(e, v1[2], acc[j][6]);
            acc[j][7] = fmaf(e, v1[3], acc[j][7]);
        }
    }
#pragma unroll
    for (int j = 0; j < 4; ++j) {
        const float inv = 1.0f / den[j];
        float4* o = (float4*)(io + (size_t)(r0 + m) * 512 + (p0 + 16 * j) * 8);
        o[0] = make_float4(acc[j][0] * inv, acc[j][1] * inv, acc[j][2] * inv, acc[j][3] * inv);
        o[1] = make_float4(acc[j][4] * inv, acc[j][5] * inv, acc[j][6] * inv, acc[j][7] * inv);
    }
}

extern "C" void kernel_launch(void* const* d_in, const int* in_sizes, int n_in,
                              void* d_out, int out_size, void* d_ws, size_t ws_size,
                              hipStream_t stream) {
    const float* x  = (const float*)d_in[0];
    const float* wq = (const float*)d_in[1];
    const float* wk = (const float*)d_in[2];
    const float* wv = (const float*)d_in[3];
    float* out = (float*)d_out;

    float* ws   = (float*)d_ws;
    float* qs   = ws;                 // 16384
    float* ks   = ws + 16384;         // 16384
    float* wqs  = ws + 32768;         // 512
    float* wks  = ws + 33280;         // 512
    float* kmax = ws + 33792;         // 256
    float* kmin = ws + 34048;         // 256
    float* L    = ws + 34304;         // 16384
    _Float16* whf = (_Float16*)(ws + 50688);    // 512*512 f16 (transposed Wv)
    _Float16* xh  = (_Float16*)(ws + 181760);   // 16384*512 f16

    hipLaunchKernelGGL(k_prep,  dim3(320),  dim3(256), 0, stream, wq, wk, wv, wqs, wks, whf);
    hipLaunchKernelGGL(k_qsks,  dim3(4096), dim3(256), 0, stream, x, wqs, wks, qs, ks, xh);
    hipLaunchKernelGGL(k_prep2, dim3(256),  dim3(64),  0, stream, ks, kmax, kmin, L);
    hipLaunchKernelGGL(k_vgemm, dim3(512),  dim3(256), 0, stream, xh, whf, out);
    hipLaunchKernelGGL(k_attn,  dim3(1024), dim3(256), 0, stream, out, qs, L, kmax, kmin);
}

// Round 10
// 132.367 us; speedup vs baseline: 1.8368x; 1.0579x over previous
//
#include <hip/hip_runtime.h>
#include <hip/hip_bf16.h>
#include <math.h>

// Problem dims (fixed): B=4, H=W=64, DIM=512, HEADS=64, QKV=8
// NPOS = 16384 positions (4096/batch).
// qs[r] = x[r,:].wq_sum ; ks[r] likewise.
// weights[r,p,q] = softmax_q(qs[r]*ks[b,p,q]*SCALE)
// out[r, p*8+d] = sum_q weights * V[r, q*8+d],  V = x @ w_v.
//
// Pipeline: k_prep (wsum + WvT f16) -> k_qsks (qs/ks + x->f16) -> k_prep2
//        -> k_vgemm (f16 MFMA, V f16 into ws) -> k_attn2 (MFMA PV w/ ones-row)

#define SCALE 0.35355339059327373f   // 8^-0.5
#define LOG2E 1.4426950408889634f

typedef __attribute__((ext_vector_type(8))) _Float16 f16x8;
typedef __attribute__((ext_vector_type(4))) _Float16 f16x4;
typedef __attribute__((ext_vector_type(4))) float f32x4;

// async global->LDS, 16B per lane (dest must be wave-linear)
__device__ __forceinline__ void gl16(const void* g, void* l) {
    __builtin_amdgcn_global_load_lds(
        (const __attribute__((address_space(1))) unsigned int*)g,
        (__attribute__((address_space(3))) unsigned int*)l, 16, 0, 0);
}

// ---------------- combined prep: blocks 0..63 Wv transform, 64..319 w-sums ----
__global__ __launch_bounds__(256) void k_prep(const float* __restrict__ wq,
                                              const float* __restrict__ wk,
                                              const float* __restrict__ wv,
                                              float* __restrict__ wqs,
                                              float* __restrict__ wks,
                                              _Float16* __restrict__ whf) {
    __shared__ float tile[64][65];
    if (blockIdx.x >= 64) {
        int gw = ((int)blockIdx.x - 64) * 4 + (threadIdx.x >> 6);  // 0..1023
        int lane = threadIdx.x & 63;
        const float* src = (gw < 512) ? wq : wk;
        int c = gw & 511;
        const float4* row = (const float4*)(src + (size_t)c * 512);
        float4 a = row[lane * 2], b = row[lane * 2 + 1];
        float s = a.x + a.y + a.z + a.w + b.x + b.y + b.z + b.w;
#pragma unroll
        for (int off = 32; off; off >>= 1) s += __shfl_xor(s, off);
        if (lane == 0) {
            if (gw < 512) wqs[c] = s; else wks[c] = s;
        }
        return;
    }
    const int ti = (int)blockIdx.x >> 3;  // k-tile
    const int tj = (int)blockIdx.x & 7;   // n-tile
    const int r = threadIdx.x >> 4;
    const int c4 = (threadIdx.x & 15) * 4;
#pragma unroll
    for (int i = 0; i < 4; ++i) {
        int kl = r + i * 16;
        float4 v = *(const float4*)(wv + (size_t)(ti * 64 + kl) * 512 + tj * 64 + c4);
        tile[kl][c4 + 0] = v.x; tile[kl][c4 + 1] = v.y;
        tile[kl][c4 + 2] = v.z; tile[kl][c4 + 3] = v.w;
    }
    __syncthreads();
#pragma unroll
    for (int i = 0; i < 4; ++i) {
        int nl = r + i * 16;
        int n = tj * 64 + nl;
        f16x4 h4;
        h4[0] = (_Float16)tile[c4 + 0][nl];
        h4[1] = (_Float16)tile[c4 + 1][nl];
        h4[2] = (_Float16)tile[c4 + 2][nl];
        h4[3] = (_Float16)tile[c4 + 3][nl];
        *(f16x4*)(whf + (size_t)n * 512 + ti * 64 + c4) = h4;
    }
}

// ---------------- qs / ks + x -> f16 copy: one wave per position ----------------
__global__ __launch_bounds__(256) void k_qsks(const float* __restrict__ x,
                                              const float* __restrict__ wqs,
                                              const float* __restrict__ wks,
                                              float* __restrict__ qs,
                                              float* __restrict__ ks,
                                              _Float16* __restrict__ xh) {
    int row = (int)blockIdx.x * 4 + (threadIdx.x >> 6);  // 0..16383
    int lane = threadIdx.x & 63;
    const float4* xr = (const float4*)(x + (size_t)row * 512);
    const float4* q4 = (const float4*)wqs;
    const float4* k4 = (const float4*)wks;
    float4 xv0 = xr[lane * 2], xv1 = xr[lane * 2 + 1];
    float4 qv0 = q4[lane * 2], qv1 = q4[lane * 2 + 1];
    float4 kv0 = k4[lane * 2], kv1 = k4[lane * 2 + 1];
    float sq = xv0.x * qv0.x + xv0.y * qv0.y + xv0.z * qv0.z + xv0.w * qv0.w
             + xv1.x * qv1.x + xv1.y * qv1.y + xv1.z * qv1.z + xv1.w * qv1.w;
    float sk = xv0.x * kv0.x + xv0.y * kv0.y + xv0.z * kv0.z + xv0.w * kv0.w
             + xv1.x * kv1.x + xv1.y * kv1.y + xv1.z * kv1.z + xv1.w * kv1.w;
    f16x8 hv;
    hv[0] = (_Float16)xv0.x; hv[1] = (_Float16)xv0.y;
    hv[2] = (_Float16)xv0.z; hv[3] = (_Float16)xv0.w;
    hv[4] = (_Float16)xv1.x; hv[5] = (_Float16)xv1.y;
    hv[6] = (_Float16)xv1.z; hv[7] = (_Float16)xv1.w;
    *(f16x8*)(xh + (size_t)row * 512 + lane * 8) = hv;
#pragma unroll
    for (int off = 32; off; off >>= 1) {
        sq += __shfl_xor(sq, off);
        sk += __shfl_xor(sk, off);
    }
    if (lane == 0) { qs[row] = sq; ks[row] = sk; }
}

// ---------------- per-(b,p) row max/min of ks ----------------
__global__ __launch_bounds__(64) void k_prep2(const float* __restrict__ ks,
                                              float* __restrict__ kmax,
                                              float* __restrict__ kmin) {
    int bp = blockIdx.x;          // b*64 + p
    int q = threadIdx.x;
    float v = ks[bp * 64 + q];
    float hi = v, lo = v;
#pragma unroll
    for (int off = 32; off; off >>= 1) {
        hi = fmaxf(hi, __shfl_xor(hi, off));
        lo = fminf(lo, __shfl_xor(lo, off));
    }
    if (q == 0) { kmax[bp] = hi; kmin[bp] = lo; }
}

// ---------------- V-GEMM: V = X @ Wv, pure-f16 MFMA, writes V as f16 ----------------
// BM=128, BN=128, BK=64. grid 512, 256 threads (4 waves 2x2), wave tile 64x64.
__global__ __launch_bounds__(256, 3) void k_vgemm(const _Float16* __restrict__ xh,
                                                  const _Float16* __restrict__ whf,
                                                  _Float16* __restrict__ vh) {
    __shared__ _Float16 As[128 * 64];
    __shared__ _Float16 Bs[128 * 64];

    const int tid = threadIdx.x;
    const int wave = tid >> 6, lane = tid & 63;
    const int mblk = (int)(blockIdx.x >> 2) * 128;
    const int nblk = (int)(blockIdx.x & 3) * 128;
    const int wm = wave >> 1, wn = wave & 1;
    const int arow = lane & 15, kgrp = lane >> 4;
    const int s7 = arow & 7;

    const _Float16* pa[4]; const _Float16* pb[4];
    _Float16* la[4]; _Float16* lb[4];
#pragma unroll
    for (int i = 0; i < 4; ++i) {
        const int g = i * 256 + tid;          // granule 0..1023
        const int row = g >> 3, gp = g & 7;
        const int gs = (gp ^ (row & 7)) * 8;  // source k-offset (halves)
        pa[i] = xh + (size_t)(mblk + row) * 512 + gs;
        pb[i] = whf + (size_t)(nblk + row) * 512 + gs;
        la[i] = As + g * 8;
        lb[i] = Bs + g * 8;
    }

    f32x4 acc[4][4];
#pragma unroll
    for (int mt = 0; mt < 4; ++mt)
#pragma unroll
        for (int nt = 0; nt < 4; ++nt) acc[mt][nt] = (f32x4){0.f, 0.f, 0.f, 0.f};

    for (int step = 0; step < 8; ++step) {
#pragma unroll
        for (int i = 0; i < 4; ++i) gl16(pa[i], la[i]);
#pragma unroll
        for (int i = 0; i < 4; ++i) gl16(pb[i], lb[i]);
#pragma unroll
        for (int i = 0; i < 4; ++i) { pa[i] += 64; pb[i] += 64; }
        __syncthreads();

#pragma unroll
        for (int sub = 0; sub < 2; ++sub) {
            f16x8 a[4], b[4];
            const int pg = ((sub * 4 + kgrp) ^ s7) * 8;
#pragma unroll
            for (int mt = 0; mt < 4; ++mt)
                a[mt] = *(const f16x8*)(As + (wm * 64 + mt * 16 + arow) * 64 + pg);
#pragma unroll
            for (int nt = 0; nt < 4; ++nt)
                b[nt] = *(const f16x8*)(Bs + (wn * 64 + nt * 16 + arow) * 64 + pg);
#pragma unroll
            for (int mt = 0; mt < 4; ++mt)
#pragma unroll
                for (int nt = 0; nt < 4; ++nt)
                    acc[mt][nt] = __builtin_amdgcn_mfma_f32_16x16x32_f16(a[mt], b[nt], acc[mt][nt], 0, 0, 0);
        }
        __syncthreads();
    }

    const int rbase = (lane >> 4) * 4;
#pragma unroll
    for (int mt = 0; mt < 4; ++mt)
#pragma unroll
        for (int nt = 0; nt < 4; ++nt) {
            const int col = nblk + wn * 64 + nt * 16 + arow;
#pragma unroll
            for (int r = 0; r < 4; ++r) {
                const int row = mblk + wm * 64 + mt * 16 + rbase + r;
                vh[(size_t)row * 512 + col] = (_Float16)acc[mt][nt][r];
            }
        }
}

// ---------------- attention via MFMA: out^T[d][p] = Vt[d][q] @ P^T[q][p] --------
// Block = 32 positions, 4 waves (8 pos/wave). Ones-row at d=8 yields softmax
// denominator in D row 8. K-values in 64 regs/lane (loaded once per block).
// Vt LDS [32 pos][9 rows][64 q] f16, granule-swizzled (slot = g ^ (d&7)).
__global__ __launch_bounds__(256, 3) void k_attn2(const _Float16* __restrict__ vh,
                                                  const float* __restrict__ qs,
                                                  const float* __restrict__ ks,
                                                  const float* __restrict__ kmax,
                                                  const float* __restrict__ kmin,
                                                  float* __restrict__ out) {
    __shared__ _Float16 Vt[32 * 576];   // 36 KB
    const int tid = threadIdx.x;
    const int r0 = (int)blockIdx.x * 32;
    const int b = r0 >> 12;
    const int lane = tid & 63, wid = tid >> 6;
    const int n = lane & 15, kgrp = lane >> 4;

    // ---- stage ones row (d=8) ----
    {
        const int r = tid >> 3, g = tid & 7;
        f16x8 ones;
#pragma unroll
        for (int i = 0; i < 8; ++i) ones[i] = (_Float16)1.0f;
        *(f16x8*)(Vt + r * 576 + 512 + g * 8) = ones;
    }
    // ---- stage Vt rows 0..7: transpose V[r][q][d] -> Vt[r][d][q], swizzled ----
#pragma unroll
    for (int c = 0; c < 8; ++c) {
        const int ch = c * 256 + tid;          // chunk 0..2047
        const int rr = ch >> 6, q = ch & 63;
        f16x8 v = *(const f16x8*)(vh + (size_t)(r0 + rr) * 512 + q * 8);
        const int gq = q >> 3, qi = q & 7;
        _Float16* base = Vt + rr * 576 + qi;
#pragma unroll
        for (int d = 0; d < 8; ++d)
            base[d * 64 + ((gq ^ d) * 8)] = v[d];
    }

    // ---- per-lane K registers (p = nt*16 + n, q = ks*32 + kgrp*8 + h*4 + i) ----
    float4 kk[4][2][2];
#pragma unroll
    for (int nt = 0; nt < 4; ++nt)
#pragma unroll
        for (int ksi = 0; ksi < 2; ++ksi)
#pragma unroll
            for (int h = 0; h < 2; ++h)
                kk[nt][ksi][h] = *(const float4*)(ks + b * 4096 + (nt * 16 + n) * 64
                                                  + ksi * 32 + kgrp * 8 + h * 4);
    float km[4], kn[4];
#pragma unroll
    for (int nt = 0; nt < 4; ++nt) {
        km[nt] = kmax[b * 64 + nt * 16 + n];
        kn[nt] = kmin[b * 64 + nt * 16 + n];
    }
    __syncthreads();

    const int m = n;                       // A-row (d) for this lane
    const bool aval = (m <= 8);
    const int abase0 = m * 64 + ((kgrp ^ (m & 7)) * 8);         // ks=0
    const int abase1 = m * 64 + (((4 + kgrp) ^ (m & 7)) * 8);   // ks=1
    const f16x8 azero = {};

    for (int it = 0; it < 8; ++it) {
        const int lp = wid * 8 + it;
        const int r = r0 + lp;
        const float t2 = qs[r] * (SCALE * LOG2E);
        const f16x8 a0 = aval ? *(const f16x8*)(Vt + lp * 576 + abase0) : azero;
        const f16x8 a1 = aval ? *(const f16x8*)(Vt + lp * 576 + abase1) : azero;

#pragma unroll
        for (int nt = 0; nt < 4; ++nt) {
            const float rm2 = (t2 >= 0.f) ? t2 * km[nt] : t2 * kn[nt];  // exact max
            f16x8 b0, b1;
#pragma unroll
            for (int h = 0; h < 2; ++h) {
                const float4 k0 = kk[nt][0][h];
                const float4 k1 = kk[nt][1][h];
                b0[h * 4 + 0] = (_Float16)exp2f(fmaf(t2, k0.x, -rm2));
                b0[h * 4 + 1] = (_Float16)exp2f(fmaf(t2, k0.y, -rm2));
                b0[h * 4 + 2] = (_Float16)exp2f(fmaf(t2, k0.z, -rm2));
                b0[h * 4 + 3] = (_Float16)exp2f(fmaf(t2, k0.w, -rm2));
                b1[h * 4 + 0] = (_Float16)exp2f(fmaf(t2, k1.x, -rm2));
                b1[h * 4 + 1] = (_Float16)exp2f(fmaf(t2, k1.y, -rm2));
                b1[h * 4 + 2] = (_Float16)exp2f(fmaf(t2, k1.z, -rm2));
                b1[h * 4 + 3] = (_Float16)exp2f(fmaf(t2, k1.w, -rm2));
            }
            f32x4 acc = (f32x4){0.f, 0.f, 0.f, 0.f};
            acc = __builtin_amdgcn_mfma_f32_16x16x32_f16(a0, b0, acc, 0, 0, 0);
            acc = __builtin_amdgcn_mfma_f32_16x16x32_f16(a1, b1, acc, 0, 0, 0);
            // D: col = lane&15 = p-within-tile, row = kgrp*4 + rr = d. Row 8 = den.
            const float den = __shfl(acc[0], 32 + n);
            const float inv = __builtin_amdgcn_rcpf(den);
            if (lane < 32) {
                float4 o = make_float4(acc[0] * inv, acc[1] * inv, acc[2] * inv, acc[3] * inv);
                *(float4*)(out + (size_t)r * 512 + (nt * 16 + n) * 8 + kgrp * 4) = o;
            }
        }
    }
}

extern "C" void kernel_launch(void* const* d_in, const int* in_sizes, int n_in,
                              void* d_out, int out_size, void* d_ws, size_t ws_size,
                              hipStream_t stream) {
    const float* x  = (const float*)d_in[0];
    const float* wq = (const float*)d_in[1];
    const float* wk = (const float*)d_in[2];
    const float* wv = (const float*)d_in[3];
    float* out = (float*)d_out;

    float* ws   = (float*)d_ws;
    float* qs   = ws;                 // 16384
    float* ks   = ws + 16384;         // 16384
    float* wqs  = ws + 32768;         // 512
    float* wks  = ws + 33280;         // 512
    float* kmax = ws + 33792;         // 256
    float* kmin = ws + 34048;         // 256
    _Float16* whf = (_Float16*)(ws + 50688);     // 512*512 f16
    _Float16* xh  = (_Float16*)(ws + 181760);    // 16384*512 f16
    _Float16* vh  = (_Float16*)(ws + 4376064);   // 16384*512 f16

    hipLaunchKernelGGL(k_prep,  dim3(320),  dim3(256), 0, stream, wq, wk, wv, wqs, wks, whf);
    hipLaunchKernelGGL(k_qsks,  dim3(4096), dim3(256), 0, stream, x, wqs, wks, qs, ks, xh);
    hipLaunchKernelGGL(k_prep2, dim3(256),  dim3(64),  0, stream, ks, kmax, kmin);
    hipLaunchKernelGGL(k_vgemm, dim3(512),  dim3(256), 0, stream, xh, whf, vh);
    hipLaunchKernelGGL(k_attn2, dim3(512),  dim3(256), 0, stream, vh, qs, ks, kmax, kmin, out);
}